// Round 12
// baseline (471.740 us; speedup 1.0000x reference)
//
#include <hip/hip_runtime.h>
#include <hip/hip_bf16.h>
#include <math.h>

// Decoder step, pointer-generator network. B=8, L=8192, H=512, E=256, V=8192.
// Device buffers are f32; y_t_prev int32. Internal bf16 MFMA for the big
// attention-feature GEMM (threshold 0.085 = bf16 floor; measured absmax 4.9e-4).
// d_out (f32) layout: P_w[65536] attn[65536] c_t[8192] cov_next[65536]
//                     h_new[4096] c_new[4096] p_gen[8]  (total 213000)
//
// Round 12: GEMM widened to 8 waves (512 thr), BM=128 BN=256, LDS 64KB ->
// 2 blocks/CU = 16 waves/CU (vs r8's 12). Same verified 2-barrier structure,
// same 64x64 wave tile / staging / swizzle formulas; only wave-grid and
// i-strides change. h logical re-read 8x -> 4x; staging instrs/thread 12 -> 8.

#define MTOT 65536   // B*L

typedef __attribute__((ext_vector_type(8))) short bf16x8;
typedef __attribute__((ext_vector_type(4))) float f32x4;
typedef unsigned int u32;

__device__ __forceinline__ float sigf(float x) { return 1.0f / (1.0f + expf(-x)); }
__device__ __forceinline__ float wave_sum(float v) {
    v += __shfl_xor(v, 1);  v += __shfl_xor(v, 2);  v += __shfl_xor(v, 4);
    v += __shfl_xor(v, 8);  v += __shfl_xor(v, 16); v += __shfl_xor(v, 32);
    return v;
}
// f32 -> bf16 bits, round-to-nearest-even (finite inputs)
__device__ __forceinline__ unsigned short f2bu(float f) {
    union { float f; unsigned int i; } c; c.f = f;
    unsigned int x = c.i;
    return (unsigned short)((x + 0x7fffu + ((x >> 16) & 1u)) >> 16);
}
// async global -> LDS, 16 bytes per lane (lds dest: wave-uniform base + lane*16)
__device__ __forceinline__ void gl16(const void* g, void* l) {
    __builtin_amdgcn_global_load_lds(
        (const __attribute__((address_space(1))) u32*)g,
        (__attribute__((address_space(3))) u32*)l, 16, 0, 0);
}

// ---------- K0 (merged): blocks 0..1023 repack Wh + extract wc/av;
//                          blocks 1024..1087 compute feed x.
__global__ void pre_kernel(const float* __restrict__ attn_W, const float* __restrict__ attn_v,
                           unsigned short* __restrict__ Whx,
                           float* __restrict__ wcf, float* __restrict__ avf,
                           const int* __restrict__ y_prev, const float* __restrict__ emb,
                           const float* __restrict__ c_t_pre,
                           const float* __restrict__ feed_W,
                           const float* __restrict__ feed_b, float* __restrict__ xo) {
    __shared__ float cat[8 * 1280];
    int tid = threadIdx.x;
    if (blockIdx.x < 1024) {
        // Wh repack
        int idx0 = blockIdx.x * 1024 + tid * 4;
        #pragma unroll
        for (int t = 0; t < 4; ++t) {
            int idx = idx0 + t;
            int m = idx >> 10, n = idx & 1023;
            Whx[idx] = f2bu(attn_W[(size_t)m * 2049 + n]);
        }
        if (blockIdx.x == 0) {
            for (int i = tid; i < 1024; i += 256) {
                wcf[i] = attn_W[(size_t)i * 2049 + 2048];
                avf[i] = attn_v[i];
            }
        }
    } else {
        // feed: x = concat(emb[y], c_t_pre) @ feed_W.T + feed_b
        int blk = blockIdx.x - 1024;   // 0..63
        for (int idx = tid; idx < 8 * 1280; idx += 256) {
            int b = idx / 1280, k = idx - b * 1280;
            cat[idx] = (k < 256) ? emb[(size_t)y_prev[b] * 256 + k]
                                 : c_t_pre[b * 1024 + (k - 256)];
        }
        __syncthreads();
        int e = blk * 4 + (tid >> 6);
        int lane = tid & 63;
        float acc[8] = {};
        for (int k = lane; k < 1280; k += 64) {
            float w = feed_W[(size_t)e * 1280 + k];
            #pragma unroll
            for (int b = 0; b < 8; ++b) acc[b] += w * cat[b * 1280 + k];
        }
        #pragma unroll
        for (int b = 0; b < 8; ++b) acc[b] = wave_sum(acc[b]);
        if (lane == 0) {
            float fb = feed_b[e];
            #pragma unroll
            for (int b = 0; b < 8; ++b) xo[b * 256 + e] = acc[b] + fb;
        }
    }
}

// ---------- K2: gates = x@Wih.T + bih + s_h@Whh.T + bhh   -> ws_gates (8,2048)
__global__ void gates_kernel(const float* __restrict__ x, const float* __restrict__ s_h,
                             const float* __restrict__ Wih, const float* __restrict__ Whh,
                             const float* __restrict__ bih, const float* __restrict__ bhh,
                             float* __restrict__ gates) {
    __shared__ float xs[8 * 256];
    __shared__ float hs[8 * 512];
    int tid = threadIdx.x;
    for (int i = tid; i < 2048; i += 256) xs[i] = x[i];
    for (int i = tid; i < 4096; i += 256) hs[i] = s_h[i];
    __syncthreads();
    int j = blockIdx.x * 4 + (tid >> 6);
    int lane = tid & 63;
    float acc[8] = {};
    for (int k = lane; k < 256; k += 64) {
        float w = Wih[(size_t)j * 256 + k];
        #pragma unroll
        for (int b = 0; b < 8; ++b) acc[b] += w * xs[b * 256 + k];
    }
    for (int k = lane; k < 512; k += 64) {
        float w = Whh[(size_t)j * 512 + k];
        #pragma unroll
        for (int b = 0; b < 8; ++b) acc[b] += w * hs[b * 512 + k];
    }
    #pragma unroll
    for (int b = 0; b < 8; ++b) acc[b] = wave_sum(acc[b]);
    if (lane == 0) {
        float bb = bih[j] + bhh[j];
        #pragma unroll
        for (int b = 0; b < 8; ++b) gates[b * 2048 + j] = acc[b] + bb;
    }
}

// ---------- K3: LSTM pointwise -> h_new,c_new (f32 out) + s_hat f32 ws
__global__ void lstm_kernel(const float* __restrict__ gates, const float* __restrict__ s_c,
                            float* __restrict__ out_h, float* __restrict__ out_c,
                            float* __restrict__ shat) {
    int idx = blockIdx.x * 256 + threadIdx.x;   // 4096
    int b = idx >> 9, u = idx & 511;
    const float* g = gates + b * 2048;
    float ig = sigf(g[u]), fg = sigf(g[512 + u]), gg = tanhf(g[1024 + u]), og = sigf(g[1536 + u]);
    float c = fg * s_c[idx] + ig * gg;
    float h = og * tanhf(c);
    out_h[idx] = h;
    out_c[idx] = c;
    shat[b * 1024 + u] = h;
    shat[b * 1024 + 512 + u] = c;
}

// ---------- K4: sterm = s_hat @ Ws.T + attn_b  -> ws_sterm (8,1024)
__global__ void sterm_kernel(const float* __restrict__ shat, const float* __restrict__ attn_W,
                             const float* __restrict__ attn_b, float* __restrict__ sterm) {
    __shared__ float ss[8 * 1024];
    int tid = threadIdx.x;
    for (int i = tid; i < 8192; i += 256) ss[i] = shat[i];
    __syncthreads();
    int m = blockIdx.x * 4 + (tid >> 6);
    int lane = tid & 63;
    float acc[8] = {};
    for (int k = lane; k < 1024; k += 64) {
        float w = attn_W[(size_t)m * 2049 + 1024 + k];
        #pragma unroll
        for (int b = 0; b < 8; ++b) acc[b] += w * ss[b * 1024 + k];
    }
    #pragma unroll
    for (int b = 0; b < 8; ++b) acc[b] = wave_sum(acc[b]);
    if (lane == 0) {
        float ab = attn_b[m];
        #pragma unroll
        for (int b = 0; b < 8; ++b) sterm[b * 1024 + m] = acc[b] + ab;
    }
}

// ---------- K5: fused GEMM, 8 waves. BM=128, BN=256, BK=64, 512 thr
// (2x4 wave grid, wave tile 64x64, acc 4x4). A staged f32 via gload_lds
// (32B-chunk XOR swizzle, inverse on src), cvt f32->bf16 via v_perm at
// fragment read. B bf16 gload_lds (16B-chunk swizzle), 256 rows.
// LDS 64KB -> 2 blocks/CU (16 waves/CU). 2-barrier loop (verified structure).
__global__ __launch_bounds__(512, 2)
void attn_gemm_kernel(const float* __restrict__ h, const unsigned short* __restrict__ Whx,
                      const float* __restrict__ sterm, const float* __restrict__ coverage,
                      const float* __restrict__ wcf, const float* __restrict__ avf,
                      float* __restrict__ scores_part) {
    __shared__ uint4 As4[2048];   // 128 rows x 256 B (64 f32) = 32KB
    __shared__ uint4 Bs4[2048];   // 256 rows x 128 B (64 bf16) = 32KB
    char* As = (char*)As4;
    char* Bs = (char*)Bs4;
    int tid = threadIdx.x;
    // XCD swizzle (2048 blocks): id = 32g + 8c + x -> rt = x + 8g, ct = c
    int id = blockIdx.x;
    int ct = (id >> 3) & 3;
    int rt = (id & 7) + ((id >> 5) << 3);
    int r0 = rt * 128, m0 = ct * 256;
    int lane = tid & 63, wid = tid >> 6;
    int wr = wid >> 2, wc = wid & 3;      // 2x4 waves, wave tile 64x64
    f32x4 acc[4][4] = {};

    // B staging: 4 instrs x 8KB (64 rows each). row = i*64 + wid*8 + lane>>3,
    // phys 16B-chunk lane&7; source chunk = (lane&7) ^ (row&7), row&7 = lane>>3.
    int lrowB = lane >> 3;
    int lsrcB = (lane & 7) ^ lrowB;
    // A staging (f32): 4 instrs x 8KB (32 rows each). row = i*32 + wid*4 +
    // (lane>>4), 16B-chunk c16 = lane&15 -> phys 32B-chunk c16>>1, half c16&1.
    // Source f32 col = ((c16>>1) ^ (row&7))*8 + (c16&1)*4.
    int rA7  = (wid * 4 + (lane >> 4)) & 7;
    int srcA = ((((lane & 15) >> 1) ^ rA7) << 3) + ((lane & 1) << 2);

    for (int t = 0; t < 16; ++t) {
        int k0 = t * 64;
        const float* hA = h + (size_t)r0 * 1024 + k0;
        const unsigned short* wB = Whx + (size_t)m0 * 1024 + k0;
        #pragma unroll
        for (int i = 0; i < 4; ++i) {   // A: 4 x 8KB (32 rows each)
            int row = i * 32 + wid * 4 + (lane >> 4);
            gl16(hA + (size_t)row * 1024 + srcA, As + i * 8192 + wid * 1024);
        }
        #pragma unroll
        for (int i = 0; i < 4; ++i) {   // B: 4 x 8KB (64 rows each, 256 total)
            int row = i * 64 + wid * 8 + lrowB;
            gl16(wB + (size_t)row * 1024 + lsrcB * 8, Bs + i * 8192 + wid * 1024);
        }
        __syncthreads();   // compiler inserts vmcnt(0): deposits complete

        #pragma unroll
        for (int kh = 0; kh < 2; ++kh) {
            int cb = kh * 4 + (lane >> 4);
            bf16x8 af[4], bfr[4];
            #pragma unroll
            for (int mi = 0; mi < 4; ++mi) {
                int row = wr * 64 + mi * 16 + (lane & 15);
                int pc = (cb ^ (row & 7)) << 5;   // phys 32B chunk
                uint4 lo = *reinterpret_cast<const uint4*>(As + row * 256 + pc);
                uint4 hi = *reinterpret_cast<const uint4*>(As + row * 256 + pc + 16);
                uint4 pk;
                pk.x = __builtin_amdgcn_perm(lo.y, lo.x, 0x07060302u);
                pk.y = __builtin_amdgcn_perm(lo.w, lo.z, 0x07060302u);
                pk.z = __builtin_amdgcn_perm(hi.y, hi.x, 0x07060302u);
                pk.w = __builtin_amdgcn_perm(hi.w, hi.z, 0x07060302u);
                af[mi] = *reinterpret_cast<bf16x8*>(&pk);
            }
            #pragma unroll
            for (int ni = 0; ni < 4; ++ni) {
                int row = wc * 64 + ni * 16 + (lane & 15);   // 0..255
                bfr[ni] = *reinterpret_cast<const bf16x8*>(Bs + row * 128 + ((cb ^ (row & 7)) << 4));
            }
            #pragma unroll
            for (int mi = 0; mi < 4; ++mi)
                #pragma unroll
                for (int ni = 0; ni < 4; ++ni)
                    acc[mi][ni] = __builtin_amdgcn_mfma_f32_16x16x32_bf16(af[mi], bfr[ni], acc[mi][ni], 0, 0, 0);
        }
        __syncthreads();   // readers done before next overwrite
    }

    // epilogue: bias + tanh + dot attn_v over this tile's 256 columns.
    float* red = (float*)As4;   // 128 rows x 4 col-waves, overlays As after barrier
    int b = r0 >> 13;
    float covv[4][4];
    #pragma unroll
    for (int mi = 0; mi < 4; ++mi)
        #pragma unroll
        for (int j = 0; j < 4; ++j)
            covv[mi][j] = coverage[r0 + wr * 64 + mi * 16 + ((lane >> 4) << 2) + j];
    float rs[4][4] = {};
    #pragma unroll
    for (int ni = 0; ni < 4; ++ni) {
        int m = m0 + wc * 64 + ni * 16 + (lane & 15);
        float stm = sterm[b * 1024 + m];
        float wcm = wcf[m], avm = avf[m];
        #pragma unroll
        for (int mi = 0; mi < 4; ++mi)
            #pragma unroll
            for (int j = 0; j < 4; ++j) {
                float val = acc[mi][ni][j] + stm + covv[mi][j] * wcm;
                rs[mi][j] += tanhf(val) * avm;
            }
    }
    #pragma unroll
    for (int mi = 0; mi < 4; ++mi)
        #pragma unroll
        for (int j = 0; j < 4; ++j) {
            float v = rs[mi][j];
            v += __shfl_xor(v, 1); v += __shfl_xor(v, 2);
            v += __shfl_xor(v, 4); v += __shfl_xor(v, 8);
            rs[mi][j] = v;
        }
    __syncthreads();   // all waves past k-loop reads before red overlays As
    if ((lane & 15) == 0) {
        int g4 = lane >> 4;
        #pragma unroll
        for (int mi = 0; mi < 4; ++mi)
            #pragma unroll
            for (int j = 0; j < 4; ++j)
                red[(wr * 64 + mi * 16 + g4 * 4 + j) * 4 + wc] = rs[mi][j];
    }
    __syncthreads();
    if (tid < 128)
        scores_part[(size_t)ct * MTOT + r0 + tid] =
            red[tid * 4] + red[tid * 4 + 1] + red[tid * 4 + 2] + red[tid * 4 + 3];
}

// ---------- K6: softmax over L per batch; attn, coverage_next (f32). 1024 thr.
__global__ void softmax_cov_kernel(const float* __restrict__ scores_part,
                                   const float* __restrict__ coverage,
                                   float* __restrict__ attn_out,
                                   float* __restrict__ cov_out,
                                   float* __restrict__ attnf) {
    __shared__ float s[8192];
    __shared__ float wred[16];
    int b = blockIdx.x, tid = threadIdx.x;
    int lane = tid & 63, wid = tid >> 6;
    float lmax = -1e30f;
    for (int l = tid; l < 8192; l += 1024) {
        float v = 0.f;
        #pragma unroll
        for (int p = 0; p < 4; ++p) v += scores_part[(size_t)p * MTOT + b * 8192 + l];
        s[l] = v;
        lmax = fmaxf(lmax, v);
    }
    #pragma unroll
    for (int o = 32; o; o >>= 1) lmax = fmaxf(lmax, __shfl_xor(lmax, o));
    if (lane == 0) wred[wid] = lmax;
    __syncthreads();
    float bmax = wred[0];
    #pragma unroll
    for (int i = 1; i < 16; ++i) bmax = fmaxf(bmax, wred[i]);
    float lsum = 0.f;
    for (int l = tid; l < 8192; l += 1024) {
        float e = expf(s[l] - bmax);
        s[l] = e;
        lsum += e;
    }
    lsum = wave_sum(lsum);
    __syncthreads();
    if (lane == 0) wred[wid] = lsum;
    __syncthreads();
    float tsum = 0.f;
    #pragma unroll
    for (int i = 0; i < 16; ++i) tsum += wred[i];
    float inv = 1.0f / tsum;
    for (int l = tid; l < 8192; l += 1024) {
        float a = s[l] * inv;
        attnf[b * 8192 + l] = a;
        attn_out[b * 8192 + l] = a;
        cov_out[b * 8192 + l] = coverage[b * 8192 + l] + a;
    }
}

// ---------- K7: c_t partial sums over L chunks (reads f32 h, memory-bound)
__global__ void ct_partial_kernel(const float* __restrict__ h,
                                  const float* __restrict__ attnf, float* __restrict__ ct_part) {
    int blk = blockIdx.x;           // 512 = 8 b x 64 chunks
    int b = blk >> 6, ch = blk & 63;
    int tid = threadIdx.x;
    float a0 = 0, a1 = 0, a2 = 0, a3 = 0;
    int rbase = b * 8192 + ch * 128;
    for (int l = 0; l < 128; ++l) {
        float a = attnf[rbase + l];
        float4 hv = *reinterpret_cast<const float4*>(h + (size_t)(rbase + l) * 1024 + tid * 4);
        a0 += a * hv.x; a1 += a * hv.y; a2 += a * hv.z; a3 += a * hv.w;
    }
    float4 o; o.x = a0; o.y = a1; o.z = a2; o.w = a3;
    *reinterpret_cast<float4*>(ct_part + (size_t)blk * 1024 + tid * 4) = o;
}

__global__ void ct_reduce_kernel(const float* __restrict__ ct_part, float* __restrict__ ctf,
                                 float* __restrict__ ct_out) {
    int idx = blockIdx.x * 256 + threadIdx.x;   // 8192
    int b = idx >> 10, n = idx & 1023;
    const float* p = ct_part + (size_t)b * 64 * 1024 + n;
    float s = 0.f;
    #pragma unroll 8
    for (int c = 0; c < 64; ++c) s += p[c * 1024];
    ctf[idx] = s;
    ct_out[idx] = s;
}

// ---------- K8a: u = concat(h_new, c_t) @ V_W.T + V_b  -> ws_u (8,512)
__global__ void u_kernel(const float* __restrict__ shat, const float* __restrict__ ctf,
                         const float* __restrict__ V_W, const float* __restrict__ V_b,
                         float* __restrict__ u) {
    __shared__ float cat[8 * 1536];
    int tid = threadIdx.x;
    for (int idx = tid; idx < 8 * 1536; idx += 256) {
        int b = idx / 1536, k = idx - b * 1536;
        cat[idx] = (k < 512) ? shat[b * 1024 + k] : ctf[b * 1024 + (k - 512)];
    }
    __syncthreads();
    int i = blockIdx.x * 4 + (tid >> 6);
    int lane = tid & 63;
    float acc[8] = {};
    for (int k = lane; k < 1536; k += 64) {
        float w = V_W[(size_t)i * 1536 + k];
        #pragma unroll
        for (int b = 0; b < 8; ++b) acc[b] += w * cat[b * 1536 + k];
    }
    #pragma unroll
    for (int b = 0; b < 8; ++b) acc[b] = wave_sum(acc[b]);
    if (lane == 0) {
        float vb = V_b[i];
        #pragma unroll
        for (int b = 0; b < 8; ++b) u[b * 512 + i] = acc[b] + vb;
    }
}

// ---------- K8p: p_gen = sigmoid(concat(c_t, s_hat, x)·pgen_W + pgen_b)
__global__ void pgen_kernel(const float* __restrict__ ctf, const float* __restrict__ shat,
                            const float* __restrict__ x, const float* __restrict__ pgen_W,
                            const float* __restrict__ pgen_b,
                            float* __restrict__ pgenf, float* __restrict__ pgen_out) {
    int tid = threadIdx.x;   // 512 threads, wave b
    int b = tid >> 6, lane = tid & 63;
    float acc = 0.f;
    for (int k = lane; k < 2304; k += 64) {
        float v;
        if (k < 1024)      v = ctf[b * 1024 + k];
        else if (k < 2048) v = shat[b * 1024 + (k - 1024)];
        else               v = x[b * 256 + (k - 2048)];
        acc += pgen_W[k] * v;
    }
    acc = wave_sum(acc);
    if (lane == 0) {
        float p = sigf(acc + pgen_b[0]);
        pgenf[b] = p;
        pgen_out[b] = p;
    }
}

// ---------- K8b: logits = u @ Vp_W.T + Vp_b  -> ws_logits (8,8192)
__global__ void logits_kernel(const float* __restrict__ u, const float* __restrict__ Vp_W,
                              const float* __restrict__ Vp_b, float* __restrict__ logits) {
    __shared__ float us[8 * 512];
    int tid = threadIdx.x;
    for (int i = tid; i < 4096; i += 256) us[i] = u[i];
    __syncthreads();
    int v = blockIdx.x * 4 + (tid >> 6);
    int lane = tid & 63;
    float acc[8] = {};
    for (int k = lane; k < 512; k += 64) {
        float w = Vp_W[(size_t)v * 512 + k];
        #pragma unroll
        for (int b = 0; b < 8; ++b) acc[b] += w * us[b * 512 + k];
    }
    #pragma unroll
    for (int b = 0; b < 8; ++b) acc[b] = wave_sum(acc[b]);
    if (lane == 0) {
        float vb = Vp_b[v];
        #pragma unroll
        for (int b = 0; b < 8; ++b) logits[b * 8192 + v] = acc[b] + vb;
    }
}

// ---------- K8c: P_vocab = softmax(logits); P_w = pg*P_vocab + (1-pg)*attn. 1024 thr.
__global__ void final_kernel(const float* __restrict__ logits, const float* __restrict__ pgenf,
                             const float* __restrict__ attnf, float* __restrict__ pw_out) {
    __shared__ float s[8192];
    __shared__ float wred[16];
    int b = blockIdx.x, tid = threadIdx.x;
    int lane = tid & 63, wid = tid >> 6;
    float lmax = -1e30f;
    for (int l = tid; l < 8192; l += 1024) {
        float v = logits[b * 8192 + l];
        s[l] = v;
        lmax = fmaxf(lmax, v);
    }
    #pragma unroll
    for (int o = 32; o; o >>= 1) lmax = fmaxf(lmax, __shfl_xor(lmax, o));
    if (lane == 0) wred[wid] = lmax;
    __syncthreads();
    float bmax = wred[0];
    #pragma unroll
    for (int i = 1; i < 16; ++i) bmax = fmaxf(bmax, wred[i]);
    float lsum = 0.f;
    for (int l = tid; l < 8192; l += 1024) {
        float e = expf(s[l] - bmax);
        s[l] = e;
        lsum += e;
    }
    lsum = wave_sum(lsum);
    __syncthreads();
    if (lane == 0) wred[wid] = lsum;
    __syncthreads();
    float tsum = 0.f;
    #pragma unroll
    for (int i = 0; i < 16; ++i) tsum += wred[i];
    float inv = 1.0f / tsum;
    float pg = pgenf[b];
    for (int l = tid; l < 8192; l += 1024) {
        float pv = s[l] * inv;
        pw_out[b * 8192 + l] = pg * pv + (1.0f - pg) * attnf[b * 8192 + l];
    }
}

extern "C" void kernel_launch(void* const* d_in, const int* in_sizes, int n_in,
                              void* d_out, int out_size, void* d_ws, size_t ws_size,
                              hipStream_t stream) {
    (void)in_sizes; (void)n_in; (void)out_size; (void)ws_size;
    const float* h        = (const float*)d_in[0];
    const float* s_h      = (const float*)d_in[1];
    const float* s_c      = (const float*)d_in[2];
    const int*   y_prev   = (const int*)d_in[3];
    const float* c_t_pre  = (const float*)d_in[4];
    const float* coverage = (const float*)d_in[5];
    const float* emb      = (const float*)d_in[6];
    const float* feed_W   = (const float*)d_in[7];
    const float* feed_b   = (const float*)d_in[8];
    const float* Wih      = (const float*)d_in[9];
    const float* Whh      = (const float*)d_in[10];
    const float* bih      = (const float*)d_in[11];
    const float* bhh      = (const float*)d_in[12];
    const float* attn_W   = (const float*)d_in[13];
    const float* attn_b   = (const float*)d_in[14];
    const float* attn_v   = (const float*)d_in[15];
    const float* pgen_W   = (const float*)d_in[16];
    const float* pgen_b   = (const float*)d_in[17];
    const float* V_W      = (const float*)d_in[18];
    const float* V_b      = (const float*)d_in[19];
    const float* Vp_W     = (const float*)d_in[20];
    const float* Vp_b     = (const float*)d_in[21];

    float* out    = (float*)d_out;
    float* o_pw   = out;
    float* o_attn = out + 65536;
    float* o_ct   = out + 131072;
    float* o_cov  = out + 139264;
    float* o_hnew = out + 204800;
    float* o_cnew = out + 208896;
    float* o_pgen = out + 212992;

    float* ws = (float*)d_ws;
    float* ws_x       = ws;
    float* ws_gates   = ws + 2048;
    float* ws_shat    = ws + 18432;
    float* ws_sterm   = ws + 26624;
    float* ws_u       = ws + 34816;
    float* ws_logits  = ws + 38912;
    float* ws_pgen    = ws + 104448;
    float* ws_wc      = ws + 105472;
    float* ws_av      = ws + 106496;
    float* ws_attnf   = ws + 107520;
    float* ws_scoresp = ws + 173056;   // 4 x 65536
    float* ws_ctpart  = ws + 697344;   // 512 x 1024
    float* ws_ctf     = ws + 1221632;  // 8192
    unsigned short* ws_whx = (unsigned short*)(ws + 1229824);  // 1024x1024 bf16 (2MB)

    pre_kernel<<<1088, 256, 0, stream>>>(attn_W, attn_v, ws_whx, ws_wc, ws_av,
                                         y_prev, emb, c_t_pre, feed_W, feed_b, ws_x);
    gates_kernel<<<512, 256, 0, stream>>>(ws_x, s_h, Wih, Whh, bih, bhh, ws_gates);
    lstm_kernel<<<16, 256, 0, stream>>>(ws_gates, s_c, o_hnew, o_cnew, ws_shat);
    sterm_kernel<<<256, 256, 0, stream>>>(ws_shat, attn_W, attn_b, ws_sterm);
    attn_gemm_kernel<<<2048, 512, 0, stream>>>(h, ws_whx, ws_sterm, coverage,
                                               ws_wc, ws_av, ws_scoresp);
    softmax_cov_kernel<<<8, 1024, 0, stream>>>(ws_scoresp, coverage, o_attn, o_cov, ws_attnf);
    ct_partial_kernel<<<512, 256, 0, stream>>>(h, ws_attnf, ws_ctpart);
    ct_reduce_kernel<<<32, 256, 0, stream>>>(ws_ctpart, ws_ctf, o_ct);
    u_kernel<<<128, 256, 0, stream>>>(ws_shat, ws_ctf, V_W, V_b, ws_u);
    pgen_kernel<<<1, 512, 0, stream>>>(ws_ctf, ws_shat, ws_x, pgen_W, pgen_b, ws_pgen, o_pgen);
    logits_kernel<<<2048, 256, 0, stream>>>(ws_u, Vp_W, Vp_b, ws_logits);
    final_kernel<<<8, 1024, 0, stream>>>(ws_logits, ws_pgen, ws_attnf, o_pw);
}

// Round 13
// 466.626 us; speedup vs baseline: 1.0110x; 1.0110x over previous
//
#include <hip/hip_runtime.h>
#include <hip/hip_bf16.h>
#include <math.h>

// Decoder step, pointer-generator network. B=8, L=8192, H=512, E=256, V=8192.
// Device buffers are f32; y_t_prev int32. Internal bf16 MFMA for the big
// attention-feature GEMM (threshold 0.085 = bf16 floor; measured absmax 4.9e-4).
// d_out (f32) layout: P_w[65536] attn[65536] c_t[8192] cov_next[65536]
//                     h_new[4096] c_new[4096] p_gen[8]  (total 213000)
//
// Round 13: hybrid staging. A reg-staged (f32 load -> v_perm pack -> bf16
// ds_write, r4's verified path) so LDS A is 16KB bf16; B via gload_lds (r8
// verbatim); fragment reads all-bf16 (r6 verbatim, conflict-free, no read
// perms). LDS 32KB -> 4-5 blocks/CU (16-20 waves, vs r8's 12). Occupancy is
// the proven lever for the 2-barrier structure (r9/r10/r12 all lost it).

#define MTOT 65536   // B*L

typedef __attribute__((ext_vector_type(8))) short bf16x8;
typedef __attribute__((ext_vector_type(4))) float f32x4;
typedef unsigned int u32;

__device__ __forceinline__ float sigf(float x) { return 1.0f / (1.0f + expf(-x)); }
__device__ __forceinline__ float wave_sum(float v) {
    v += __shfl_xor(v, 1);  v += __shfl_xor(v, 2);  v += __shfl_xor(v, 4);
    v += __shfl_xor(v, 8);  v += __shfl_xor(v, 16); v += __shfl_xor(v, 32);
    return v;
}
// f32 -> bf16 bits, round-to-nearest-even (finite inputs)
__device__ __forceinline__ unsigned short f2bu(float f) {
    union { float f; unsigned int i; } c; c.f = f;
    unsigned int x = c.i;
    return (unsigned short)((x + 0x7fffu + ((x >> 16) & 1u)) >> 16);
}
// async global -> LDS, 16 bytes per lane (lds dest: wave-uniform base + lane*16)
__device__ __forceinline__ void gl16(const void* g, void* l) {
    __builtin_amdgcn_global_load_lds(
        (const __attribute__((address_space(1))) u32*)g,
        (__attribute__((address_space(3))) u32*)l, 16, 0, 0);
}

// ---------- K0 (merged): blocks 0..1023 repack Wh + extract wc/av;
//                          blocks 1024..1087 compute feed x.
__global__ void pre_kernel(const float* __restrict__ attn_W, const float* __restrict__ attn_v,
                           unsigned short* __restrict__ Whx,
                           float* __restrict__ wcf, float* __restrict__ avf,
                           const int* __restrict__ y_prev, const float* __restrict__ emb,
                           const float* __restrict__ c_t_pre,
                           const float* __restrict__ feed_W,
                           const float* __restrict__ feed_b, float* __restrict__ xo) {
    __shared__ float cat[8 * 1280];
    int tid = threadIdx.x;
    if (blockIdx.x < 1024) {
        // Wh repack
        int idx0 = blockIdx.x * 1024 + tid * 4;
        #pragma unroll
        for (int t = 0; t < 4; ++t) {
            int idx = idx0 + t;
            int m = idx >> 10, n = idx & 1023;
            Whx[idx] = f2bu(attn_W[(size_t)m * 2049 + n]);
        }
        if (blockIdx.x == 0) {
            for (int i = tid; i < 1024; i += 256) {
                wcf[i] = attn_W[(size_t)i * 2049 + 2048];
                avf[i] = attn_v[i];
            }
        }
    } else {
        // feed: x = concat(emb[y], c_t_pre) @ feed_W.T + feed_b
        int blk = blockIdx.x - 1024;   // 0..63
        for (int idx = tid; idx < 8 * 1280; idx += 256) {
            int b = idx / 1280, k = idx - b * 1280;
            cat[idx] = (k < 256) ? emb[(size_t)y_prev[b] * 256 + k]
                                 : c_t_pre[b * 1024 + (k - 256)];
        }
        __syncthreads();
        int e = blk * 4 + (tid >> 6);
        int lane = tid & 63;
        float acc[8] = {};
        for (int k = lane; k < 1280; k += 64) {
            float w = feed_W[(size_t)e * 1280 + k];
            #pragma unroll
            for (int b = 0; b < 8; ++b) acc[b] += w * cat[b * 1280 + k];
        }
        #pragma unroll
        for (int b = 0; b < 8; ++b) acc[b] = wave_sum(acc[b]);
        if (lane == 0) {
            float fb = feed_b[e];
            #pragma unroll
            for (int b = 0; b < 8; ++b) xo[b * 256 + e] = acc[b] + fb;
        }
    }
}

// ---------- K2: gates = x@Wih.T + bih + s_h@Whh.T + bhh   -> ws_gates (8,2048)
__global__ void gates_kernel(const float* __restrict__ x, const float* __restrict__ s_h,
                             const float* __restrict__ Wih, const float* __restrict__ Whh,
                             const float* __restrict__ bih, const float* __restrict__ bhh,
                             float* __restrict__ gates) {
    __shared__ float xs[8 * 256];
    __shared__ float hs[8 * 512];
    int tid = threadIdx.x;
    for (int i = tid; i < 2048; i += 256) xs[i] = x[i];
    for (int i = tid; i < 4096; i += 256) hs[i] = s_h[i];
    __syncthreads();
    int j = blockIdx.x * 4 + (tid >> 6);
    int lane = tid & 63;
    float acc[8] = {};
    for (int k = lane; k < 256; k += 64) {
        float w = Wih[(size_t)j * 256 + k];
        #pragma unroll
        for (int b = 0; b < 8; ++b) acc[b] += w * xs[b * 256 + k];
    }
    for (int k = lane; k < 512; k += 64) {
        float w = Whh[(size_t)j * 512 + k];
        #pragma unroll
        for (int b = 0; b < 8; ++b) acc[b] += w * hs[b * 512 + k];
    }
    #pragma unroll
    for (int b = 0; b < 8; ++b) acc[b] = wave_sum(acc[b]);
    if (lane == 0) {
        float bb = bih[j] + bhh[j];
        #pragma unroll
        for (int b = 0; b < 8; ++b) gates[b * 2048 + j] = acc[b] + bb;
    }
}

// ---------- K3: LSTM pointwise -> h_new,c_new (f32 out) + s_hat f32 ws
__global__ void lstm_kernel(const float* __restrict__ gates, const float* __restrict__ s_c,
                            float* __restrict__ out_h, float* __restrict__ out_c,
                            float* __restrict__ shat) {
    int idx = blockIdx.x * 256 + threadIdx.x;   // 4096
    int b = idx >> 9, u = idx & 511;
    const float* g = gates + b * 2048;
    float ig = sigf(g[u]), fg = sigf(g[512 + u]), gg = tanhf(g[1024 + u]), og = sigf(g[1536 + u]);
    float c = fg * s_c[idx] + ig * gg;
    float h = og * tanhf(c);
    out_h[idx] = h;
    out_c[idx] = c;
    shat[b * 1024 + u] = h;
    shat[b * 1024 + 512 + u] = c;
}

// ---------- K4: sterm = s_hat @ Ws.T + attn_b  -> ws_sterm (8,1024)
__global__ void sterm_kernel(const float* __restrict__ shat, const float* __restrict__ attn_W,
                             const float* __restrict__ attn_b, float* __restrict__ sterm) {
    __shared__ float ss[8 * 1024];
    int tid = threadIdx.x;
    for (int i = tid; i < 8192; i += 256) ss[i] = shat[i];
    __syncthreads();
    int m = blockIdx.x * 4 + (tid >> 6);
    int lane = tid & 63;
    float acc[8] = {};
    for (int k = lane; k < 1024; k += 64) {
        float w = attn_W[(size_t)m * 2049 + 1024 + k];
        #pragma unroll
        for (int b = 0; b < 8; ++b) acc[b] += w * ss[b * 1024 + k];
    }
    #pragma unroll
    for (int b = 0; b < 8; ++b) acc[b] = wave_sum(acc[b]);
    if (lane == 0) {
        float ab = attn_b[m];
        #pragma unroll
        for (int b = 0; b < 8; ++b) sterm[b * 1024 + m] = acc[b] + ab;
    }
}

// ---------- K5: hybrid GEMM. BM=BN=128, BK=64, 256 thr (2x2 waves, 64x64
// wave tile, acc 4x4). A: reg-staged f32->bf16 (load 2x uint4, v_perm pack,
// ds_write_b128 into XOR-swizzled 16KB bf16 buffer). B: gload_lds bf16 16KB
// (swizzle folded into global src). Reads: all-bf16, conflict-free, no perms.
// LDS 32KB -> 4-5 blocks/CU. 2-barrier loop (verified structure).
__global__ __launch_bounds__(256, 4)
void attn_gemm_kernel(const float* __restrict__ h, const unsigned short* __restrict__ Whx,
                      const float* __restrict__ sterm, const float* __restrict__ coverage,
                      const float* __restrict__ wcf, const float* __restrict__ avf,
                      float* __restrict__ scores_part) {
    __shared__ uint4 As4[1024];   // 128 rows x 128 B (64 bf16) = 16KB
    __shared__ uint4 Bs4[1024];   // 128 rows x 128 B (64 bf16) = 16KB
    char* As = (char*)As4;
    char* Bs = (char*)Bs4;
    int tid = threadIdx.x;
    // XCD swizzle: id = 64g + 8c + x -> rt = x + 8g (same XCD for all 8 ct), ct = c
    int id = blockIdx.x;
    int ct = (id >> 3) & 7;
    int rt = (id & 7) + ((id >> 6) << 3);
    int r0 = rt * 128, m0 = ct * 128;
    int lane = tid & 63, wid = tid >> 6;
    int wr = wid >> 1, wc = wid & 1;      // 2x2 waves, wave tile 64x64
    f32x4 acc[4][4] = {};

    // B staging (gload_lds): lane deposits 16B at row (i*32 + wid*8 + lane>>3),
    // phys chunk lane&7; source chunk = (lane&7) ^ (row&7); row&7 == lane>>3.
    int lrowB = lane >> 3;
    int lsrcB = (lane & 7) ^ lrowB;

    for (int t = 0; t < 16; ++t) {
        int k0 = t * 64;
        // A reg-stage: 1024 16B-chunks; per thread 4. chunk cidx: row=cidx>>3,
        // logical 8-bf16 chunk c=cidx&7, phys offset (c ^ (row&7))<<4.
        #pragma unroll
        for (int i = 0; i < 4; ++i) {
            int cidx = i * 256 + tid;
            int row = cidx >> 3, c = cidx & 7;
            int sw = (c ^ (row & 7)) << 4;
            const float* ap = h + (size_t)(r0 + row) * 1024 + k0 + c * 8;
            uint4 a0 = *reinterpret_cast<const uint4*>(ap);
            uint4 a1 = *reinterpret_cast<const uint4*>(ap + 4);
            uint4 pk;
            pk.x = __builtin_amdgcn_perm(a0.y, a0.x, 0x07060302u);
            pk.y = __builtin_amdgcn_perm(a0.w, a0.z, 0x07060302u);
            pk.z = __builtin_amdgcn_perm(a1.y, a1.x, 0x07060302u);
            pk.w = __builtin_amdgcn_perm(a1.w, a1.z, 0x07060302u);
            *reinterpret_cast<uint4*>(As + row * 128 + sw) = pk;
        }
        // B staging via gload_lds (r8 verbatim)
        const unsigned short* wB = Whx + (size_t)m0 * 1024 + k0;
        #pragma unroll
        for (int i = 0; i < 4; ++i) {
            int row = i * 32 + wid * 8 + lrowB;
            gl16(wB + (size_t)row * 1024 + lsrcB * 8, Bs + i * 4096 + wid * 1024);
        }
        __syncthreads();   // waits vmcnt(0) + lgkmcnt(0): both deposits complete

        #pragma unroll
        for (int kh = 0; kh < 2; ++kh) {
            int cb = kh * 4 + (lane >> 4);
            bf16x8 af[4], bfr[4];
            #pragma unroll
            for (int mi = 0; mi < 4; ++mi) {
                int row = wr * 64 + mi * 16 + (lane & 15);
                af[mi] = *reinterpret_cast<const bf16x8*>(As + row * 128 + ((cb ^ (row & 7)) << 4));
            }
            #pragma unroll
            for (int ni = 0; ni < 4; ++ni) {
                int row = wc * 64 + ni * 16 + (lane & 15);
                bfr[ni] = *reinterpret_cast<const bf16x8*>(Bs + row * 128 + ((cb ^ (row & 7)) << 4));
            }
            #pragma unroll
            for (int mi = 0; mi < 4; ++mi)
                #pragma unroll
                for (int ni = 0; ni < 4; ++ni)
                    acc[mi][ni] = __builtin_amdgcn_mfma_f32_16x16x32_bf16(af[mi], bfr[ni], acc[mi][ni], 0, 0, 0);
        }
        __syncthreads();   // readers done before next overwrite
    }

    // epilogue: bias + tanh + dot attn_v, reduce over this tile's 128 columns.
    float* red = (float*)As4;   // overlays As after barrier below
    int b = r0 >> 13;
    float covv[4][4];
    #pragma unroll
    for (int mi = 0; mi < 4; ++mi)
        #pragma unroll
        for (int j = 0; j < 4; ++j)
            covv[mi][j] = coverage[r0 + wr * 64 + mi * 16 + ((lane >> 4) << 2) + j];
    float rs[4][4] = {};
    #pragma unroll
    for (int ni = 0; ni < 4; ++ni) {
        int m = m0 + wc * 64 + ni * 16 + (lane & 15);
        float stm = sterm[b * 1024 + m];
        float wcm = wcf[m], avm = avf[m];
        #pragma unroll
        for (int mi = 0; mi < 4; ++mi)
            #pragma unroll
            for (int j = 0; j < 4; ++j) {
                float val = acc[mi][ni][j] + stm + covv[mi][j] * wcm;
                rs[mi][j] += tanhf(val) * avm;
            }
    }
    #pragma unroll
    for (int mi = 0; mi < 4; ++mi)
        #pragma unroll
        for (int j = 0; j < 4; ++j) {
            float v = rs[mi][j];
            v += __shfl_xor(v, 1); v += __shfl_xor(v, 2);
            v += __shfl_xor(v, 4); v += __shfl_xor(v, 8);
            rs[mi][j] = v;
        }
    __syncthreads();   // all waves past k-loop reads before red overlays As
    if ((lane & 15) == 0) {
        int g4 = lane >> 4;
        #pragma unroll
        for (int mi = 0; mi < 4; ++mi)
            #pragma unroll
            for (int j = 0; j < 4; ++j)
                red[(wr * 64 + mi * 16 + g4 * 4 + j) * 2 + wc] = rs[mi][j];
    }
    __syncthreads();
    if (tid < 128)
        scores_part[(size_t)ct * MTOT + r0 + tid] = red[tid * 2] + red[tid * 2 + 1];
}

// ---------- K6: softmax over L per batch; attn, coverage_next (f32). 1024 thr.
__global__ void softmax_cov_kernel(const float* __restrict__ scores_part,
                                   const float* __restrict__ coverage,
                                   float* __restrict__ attn_out,
                                   float* __restrict__ cov_out,
                                   float* __restrict__ attnf) {
    __shared__ float s[8192];
    __shared__ float wred[16];
    int b = blockIdx.x, tid = threadIdx.x;
    int lane = tid & 63, wid = tid >> 6;
    float lmax = -1e30f;
    for (int l = tid; l < 8192; l += 1024) {
        float v = 0.f;
        #pragma unroll
        for (int p = 0; p < 8; ++p) v += scores_part[(size_t)p * MTOT + b * 8192 + l];
        s[l] = v;
        lmax = fmaxf(lmax, v);
    }
    #pragma unroll
    for (int o = 32; o; o >>= 1) lmax = fmaxf(lmax, __shfl_xor(lmax, o));
    if (lane == 0) wred[wid] = lmax;
    __syncthreads();
    float bmax = wred[0];
    #pragma unroll
    for (int i = 1; i < 16; ++i) bmax = fmaxf(bmax, wred[i]);
    float lsum = 0.f;
    for (int l = tid; l < 8192; l += 1024) {
        float e = expf(s[l] - bmax);
        s[l] = e;
        lsum += e;
    }
    lsum = wave_sum(lsum);
    __syncthreads();
    if (lane == 0) wred[wid] = lsum;
    __syncthreads();
    float tsum = 0.f;
    #pragma unroll
    for (int i = 0; i < 16; ++i) tsum += wred[i];
    float inv = 1.0f / tsum;
    for (int l = tid; l < 8192; l += 1024) {
        float a = s[l] * inv;
        attnf[b * 8192 + l] = a;
        attn_out[b * 8192 + l] = a;
        cov_out[b * 8192 + l] = coverage[b * 8192 + l] + a;
    }
}

// ---------- K7: c_t partial sums over L chunks (reads f32 h, memory-bound)
__global__ void ct_partial_kernel(const float* __restrict__ h,
                                  const float* __restrict__ attnf, float* __restrict__ ct_part) {
    int blk = blockIdx.x;           // 512 = 8 b x 64 chunks
    int b = blk >> 6, ch = blk & 63;
    int tid = threadIdx.x;
    float a0 = 0, a1 = 0, a2 = 0, a3 = 0;
    int rbase = b * 8192 + ch * 128;
    for (int l = 0; l < 128; ++l) {
        float a = attnf[rbase + l];
        float4 hv = *reinterpret_cast<const float4*>(h + (size_t)(rbase + l) * 1024 + tid * 4);
        a0 += a * hv.x; a1 += a * hv.y; a2 += a * hv.z; a3 += a * hv.w;
    }
    float4 o; o.x = a0; o.y = a1; o.z = a2; o.w = a3;
    *reinterpret_cast<float4*>(ct_part + (size_t)blk * 1024 + tid * 4) = o;
}

__global__ void ct_reduce_kernel(const float* __restrict__ ct_part, float* __restrict__ ctf,
                                 float* __restrict__ ct_out) {
    int idx = blockIdx.x * 256 + threadIdx.x;   // 8192
    int b = idx >> 10, n = idx & 1023;
    const float* p = ct_part + (size_t)b * 64 * 1024 + n;
    float s = 0.f;
    #pragma unroll 8
    for (int c = 0; c < 64; ++c) s += p[c * 1024];
    ctf[idx] = s;
    ct_out[idx] = s;
}

// ---------- K8a: u = concat(h_new, c_t) @ V_W.T + V_b  -> ws_u (8,512)
__global__ void u_kernel(const float* __restrict__ shat, const float* __restrict__ ctf,
                         const float* __restrict__ V_W, const float* __restrict__ V_b,
                         float* __restrict__ u) {
    __shared__ float cat[8 * 1536];
    int tid = threadIdx.x;
    for (int idx = tid; idx < 8 * 1536; idx += 256) {
        int b = idx / 1536, k = idx - b * 1536;
        cat[idx] = (k < 512) ? shat[b * 1024 + k] : ctf[b * 1024 + (k - 512)];
    }
    __syncthreads();
    int i = blockIdx.x * 4 + (tid >> 6);
    int lane = tid & 63;
    float acc[8] = {};
    for (int k = lane; k < 1536; k += 64) {
        float w = V_W[(size_t)i * 1536 + k];
        #pragma unroll
        for (int b = 0; b < 8; ++b) acc[b] += w * cat[b * 1536 + k];
    }
    #pragma unroll
    for (int b = 0; b < 8; ++b) acc[b] = wave_sum(acc[b]);
    if (lane == 0) {
        float vb = V_b[i];
        #pragma unroll
        for (int b = 0; b < 8; ++b) u[b * 512 + i] = acc[b] + vb;
    }
}

// ---------- K8p: p_gen = sigmoid(concat(c_t, s_hat, x)·pgen_W + pgen_b)
__global__ void pgen_kernel(const float* __restrict__ ctf, const float* __restrict__ shat,
                            const float* __restrict__ x, const float* __restrict__ pgen_W,
                            const float* __restrict__ pgen_b,
                            float* __restrict__ pgenf, float* __restrict__ pgen_out) {
    int tid = threadIdx.x;   // 512 threads, wave b
    int b = tid >> 6, lane = tid & 63;
    float acc = 0.f;
    for (int k = lane; k < 2304; k += 64) {
        float v;
        if (k < 1024)      v = ctf[b * 1024 + k];
        else if (k < 2048) v = shat[b * 1024 + (k - 1024)];
        else               v = x[b * 256 + (k - 2048)];
        acc += pgen_W[k] * v;
    }
    acc = wave_sum(acc);
    if (lane == 0) {
        float p = sigf(acc + pgen_b[0]);
        pgenf[b] = p;
        pgen_out[b] = p;
    }
}

// ---------- K8b: logits = u @ Vp_W.T + Vp_b  -> ws_logits (8,8192)
__global__ void logits_kernel(const float* __restrict__ u, const float* __restrict__ Vp_W,
                              const float* __restrict__ Vp_b, float* __restrict__ logits) {
    __shared__ float us[8 * 512];
    int tid = threadIdx.x;
    for (int i = tid; i < 4096; i += 256) us[i] = u[i];
    __syncthreads();
    int v = blockIdx.x * 4 + (tid >> 6);
    int lane = tid & 63;
    float acc[8] = {};
    for (int k = lane; k < 512; k += 64) {
        float w = Vp_W[(size_t)v * 512 + k];
        #pragma unroll
        for (int b = 0; b < 8; ++b) acc[b] += w * us[b * 512 + k];
    }
    #pragma unroll
    for (int b = 0; b < 8; ++b) acc[b] = wave_sum(acc[b]);
    if (lane == 0) {
        float vb = Vp_b[v];
        #pragma unroll
        for (int b = 0; b < 8; ++b) logits[b * 8192 + v] = acc[b] + vb;
    }
}

// ---------- K8c: P_vocab = softmax(logits); P_w = pg*P_vocab + (1-pg)*attn. 1024 thr.
__global__ void final_kernel(const float* __restrict__ logits, const float* __restrict__ pgenf,
                             const float* __restrict__ attnf, float* __restrict__ pw_out) {
    __shared__ float s[8192];
    __shared__ float wred[16];
    int b = blockIdx.x, tid = threadIdx.x;
    int lane = tid & 63, wid = tid >> 6;
    float lmax = -1e30f;
    for (int l = tid; l < 8192; l += 1024) {
        float v = logits[b * 8192 + l];
        s[l] = v;
        lmax = fmaxf(lmax, v);
    }
    #pragma unroll
    for (int o = 32; o; o >>= 1) lmax = fmaxf(lmax, __shfl_xor(lmax, o));
    if (lane == 0) wred[wid] = lmax;
    __syncthreads();
    float bmax = wred[0];
    #pragma unroll
    for (int i = 1; i < 16; ++i) bmax = fmaxf(bmax, wred[i]);
    float lsum = 0.f;
    for (int l = tid; l < 8192; l += 1024) {
        float e = expf(s[l] - bmax);
        s[l] = e;
        lsum += e;
    }
    lsum = wave_sum(lsum);
    __syncthreads();
    if (lane == 0) wred[wid] = lsum;
    __syncthreads();
    float tsum = 0.f;
    #pragma unroll
    for (int i = 0; i < 16; ++i) tsum += wred[i];
    float inv = 1.0f / tsum;
    float pg = pgenf[b];
    for (int l = tid; l < 8192; l += 1024) {
        float pv = s[l] * inv;
        pw_out[b * 8192 + l] = pg * pv + (1.0f - pg) * attnf[b * 8192 + l];
    }
}

extern "C" void kernel_launch(void* const* d_in, const int* in_sizes, int n_in,
                              void* d_out, int out_size, void* d_ws, size_t ws_size,
                              hipStream_t stream) {
    (void)in_sizes; (void)n_in; (void)out_size; (void)ws_size;
    const float* h        = (const float*)d_in[0];
    const float* s_h      = (const float*)d_in[1];
    const float* s_c      = (const float*)d_in[2];
    const int*   y_prev   = (const int*)d_in[3];
    const float* c_t_pre  = (const float*)d_in[4];
    const float* coverage = (const float*)d_in[5];
    const float* emb      = (const float*)d_in[6];
    const float* feed_W   = (const float*)d_in[7];
    const float* feed_b   = (const float*)d_in[8];
    const float* Wih      = (const float*)d_in[9];
    const float* Whh      = (const float*)d_in[10];
    const float* bih      = (const float*)d_in[11];
    const float* bhh      = (const float*)d_in[12];
    const float* attn_W   = (const float*)d_in[13];
    const float* attn_b   = (const float*)d_in[14];
    const float* attn_v   = (const float*)d_in[15];
    const float* pgen_W   = (const float*)d_in[16];
    const float* pgen_b   = (const float*)d_in[17];
    const float* V_W      = (const float*)d_in[18];
    const float* V_b      = (const float*)d_in[19];
    const float* Vp_W     = (const float*)d_in[20];
    const float* Vp_b     = (const float*)d_in[21];

    float* out    = (float*)d_out;
    float* o_pw   = out;
    float* o_attn = out + 65536;
    float* o_ct   = out + 131072;
    float* o_cov  = out + 139264;
    float* o_hnew = out + 204800;
    float* o_cnew = out + 208896;
    float* o_pgen = out + 212992;

    float* ws = (float*)d_ws;
    float* ws_x       = ws;
    float* ws_gates   = ws + 2048;
    float* ws_shat    = ws + 18432;
    float* ws_sterm   = ws + 26624;
    float* ws_u       = ws + 34816;
    float* ws_logits  = ws + 38912;
    float* ws_pgen    = ws + 104448;
    float* ws_wc      = ws + 105472;
    float* ws_av      = ws + 106496;
    float* ws_attnf   = ws + 107520;
    float* ws_scoresp = ws + 173056;   // 8 x 65536
    float* ws_ctpart  = ws + 697344;   // 512 x 1024
    float* ws_ctf     = ws + 1221632;  // 8192
    unsigned short* ws_whx = (unsigned short*)(ws + 1229824);  // 1024x1024 bf16 (2MB)

    pre_kernel<<<1088, 256, 0, stream>>>(attn_W, attn_v, ws_whx, ws_wc, ws_av,
                                         y_prev, emb, c_t_pre, feed_W, feed_b, ws_x);
    gates_kernel<<<512, 256, 0, stream>>>(ws_x, s_h, Wih, Whh, bih, bhh, ws_gates);
    lstm_kernel<<<16, 256, 0, stream>>>(ws_gates, s_c, o_hnew, o_cnew, ws_shat);
    sterm_kernel<<<256, 256, 0, stream>>>(ws_shat, attn_W, attn_b, ws_sterm);
    attn_gemm_kernel<<<4096, 256, 0, stream>>>(h, ws_whx, ws_sterm, coverage,
                                               ws_wc, ws_av, ws_scoresp);
    softmax_cov_kernel<<<8, 1024, 0, stream>>>(ws_scoresp, coverage, o_attn, o_cov, ws_attnf);
    ct_partial_kernel<<<512, 256, 0, stream>>>(h, ws_attnf, ws_ctpart);
    ct_reduce_kernel<<<32, 256, 0, stream>>>(ws_ctpart, ws_ctf, o_ct);
    u_kernel<<<128, 256, 0, stream>>>(ws_shat, ws_ctf, V_W, V_b, ws_u);
    pgen_kernel<<<1, 512, 0, stream>>>(ws_ctf, ws_shat, ws_x, pgen_W, pgen_b, ws_pgen, o_pgen);
    logits_kernel<<<2048, 256, 0, stream>>>(ws_u, Vp_W, Vp_b, ws_logits);
    final_kernel<<<8, 1024, 0, stream>>>(ws_logits, ws_pgen, ws_attnf, o_pw);
}

// Round 14
// 370.263 us; speedup vs baseline: 1.2741x; 1.2603x over previous
//
#include <hip/hip_runtime.h>
#include <hip/hip_bf16.h>
#include <math.h>

// Decoder step, pointer-generator network. B=8, L=8192, H=512, E=256, V=8192.
// Device buffers are f32; y_t_prev int32. Internal bf16 MFMA for the big
// attention-feature GEMM (threshold 0.085 = bf16 floor; measured absmax 4.9e-4).
// d_out (f32) layout: P_w[65536] attn[65536] c_t[8192] cov_next[65536]
//                     h_new[4096] c_new[4096] p_gen[8]  (total 213000)
//
// Round 14: FINAL — r11 verbatim (verified 373.2us). The 2-barrier gload_lds
// GEMM at 3 blocks/CU (269us, MfmaUtil 22%) is the measured optimum of this
// structure family: r9 (wide tile), r10 (counted vmcnt), r12 (8 waves),
// r13 (hybrid staging) all regressed 4-120%. The 8-phase path requires a
// bf16-A pre-pass measured at ~160us (r6/r7), which cancels its GEMM saving.

#define MTOT 65536   // B*L

typedef __attribute__((ext_vector_type(8))) short bf16x8;
typedef __attribute__((ext_vector_type(4))) float f32x4;
typedef unsigned int u32;

__device__ __forceinline__ float sigf(float x) { return 1.0f / (1.0f + expf(-x)); }
__device__ __forceinline__ float wave_sum(float v) {
    v += __shfl_xor(v, 1);  v += __shfl_xor(v, 2);  v += __shfl_xor(v, 4);
    v += __shfl_xor(v, 8);  v += __shfl_xor(v, 16); v += __shfl_xor(v, 32);
    return v;
}
// f32 -> bf16 bits, round-to-nearest-even (finite inputs)
__device__ __forceinline__ unsigned short f2bu(float f) {
    union { float f; unsigned int i; } c; c.f = f;
    unsigned int x = c.i;
    return (unsigned short)((x + 0x7fffu + ((x >> 16) & 1u)) >> 16);
}
// async global -> LDS, 16 bytes per lane (lds dest: wave-uniform base + lane*16)
__device__ __forceinline__ void gl16(const void* g, void* l) {
    __builtin_amdgcn_global_load_lds(
        (const __attribute__((address_space(1))) u32*)g,
        (__attribute__((address_space(3))) u32*)l, 16, 0, 0);
}

// ---------- K0 (merged): blocks 0..1023 repack Wh + extract wc/av;
//                          blocks 1024..1087 compute feed x.
__global__ void pre_kernel(const float* __restrict__ attn_W, const float* __restrict__ attn_v,
                           unsigned short* __restrict__ Whx,
                           float* __restrict__ wcf, float* __restrict__ avf,
                           const int* __restrict__ y_prev, const float* __restrict__ emb,
                           const float* __restrict__ c_t_pre,
                           const float* __restrict__ feed_W,
                           const float* __restrict__ feed_b, float* __restrict__ xo) {
    __shared__ float cat[8 * 1280];
    int tid = threadIdx.x;
    if (blockIdx.x < 1024) {
        // Wh repack
        int idx0 = blockIdx.x * 1024 + tid * 4;
        #pragma unroll
        for (int t = 0; t < 4; ++t) {
            int idx = idx0 + t;
            int m = idx >> 10, n = idx & 1023;
            Whx[idx] = f2bu(attn_W[(size_t)m * 2049 + n]);
        }
        if (blockIdx.x == 0) {
            for (int i = tid; i < 1024; i += 256) {
                wcf[i] = attn_W[(size_t)i * 2049 + 2048];
                avf[i] = attn_v[i];
            }
        }
    } else {
        // feed: x = concat(emb[y], c_t_pre) @ feed_W.T + feed_b
        int blk = blockIdx.x - 1024;   // 0..63
        for (int idx = tid; idx < 8 * 1280; idx += 256) {
            int b = idx / 1280, k = idx - b * 1280;
            cat[idx] = (k < 256) ? emb[(size_t)y_prev[b] * 256 + k]
                                 : c_t_pre[b * 1024 + (k - 256)];
        }
        __syncthreads();
        int e = blk * 4 + (tid >> 6);
        int lane = tid & 63;
        float acc[8] = {};
        for (int k = lane; k < 1280; k += 64) {
            float w = feed_W[(size_t)e * 1280 + k];
            #pragma unroll
            for (int b = 0; b < 8; ++b) acc[b] += w * cat[b * 1280 + k];
        }
        #pragma unroll
        for (int b = 0; b < 8; ++b) acc[b] = wave_sum(acc[b]);
        if (lane == 0) {
            float fb = feed_b[e];
            #pragma unroll
            for (int b = 0; b < 8; ++b) xo[b * 256 + e] = acc[b] + fb;
        }
    }
}

// ---------- K2: gates = x@Wih.T + bih + s_h@Whh.T + bhh   -> ws_gates (8,2048)
__global__ void gates_kernel(const float* __restrict__ x, const float* __restrict__ s_h,
                             const float* __restrict__ Wih, const float* __restrict__ Whh,
                             const float* __restrict__ bih, const float* __restrict__ bhh,
                             float* __restrict__ gates) {
    __shared__ float xs[8 * 256];
    __shared__ float hs[8 * 512];
    int tid = threadIdx.x;
    for (int i = tid; i < 2048; i += 256) xs[i] = x[i];
    for (int i = tid; i < 4096; i += 256) hs[i] = s_h[i];
    __syncthreads();
    int j = blockIdx.x * 4 + (tid >> 6);
    int lane = tid & 63;
    float acc[8] = {};
    for (int k = lane; k < 256; k += 64) {
        float w = Wih[(size_t)j * 256 + k];
        #pragma unroll
        for (int b = 0; b < 8; ++b) acc[b] += w * xs[b * 256 + k];
    }
    for (int k = lane; k < 512; k += 64) {
        float w = Whh[(size_t)j * 512 + k];
        #pragma unroll
        for (int b = 0; b < 8; ++b) acc[b] += w * hs[b * 512 + k];
    }
    #pragma unroll
    for (int b = 0; b < 8; ++b) acc[b] = wave_sum(acc[b]);
    if (lane == 0) {
        float bb = bih[j] + bhh[j];
        #pragma unroll
        for (int b = 0; b < 8; ++b) gates[b * 2048 + j] = acc[b] + bb;
    }
}

// ---------- K3: LSTM pointwise -> h_new,c_new (f32 out) + s_hat f32 ws
__global__ void lstm_kernel(const float* __restrict__ gates, const float* __restrict__ s_c,
                            float* __restrict__ out_h, float* __restrict__ out_c,
                            float* __restrict__ shat) {
    int idx = blockIdx.x * 256 + threadIdx.x;   // 4096
    int b = idx >> 9, u = idx & 511;
    const float* g = gates + b * 2048;
    float ig = sigf(g[u]), fg = sigf(g[512 + u]), gg = tanhf(g[1024 + u]), og = sigf(g[1536 + u]);
    float c = fg * s_c[idx] + ig * gg;
    float h = og * tanhf(c);
    out_h[idx] = h;
    out_c[idx] = c;
    shat[b * 1024 + u] = h;
    shat[b * 1024 + 512 + u] = c;
}

// ---------- K4: sterm = s_hat @ Ws.T + attn_b  -> ws_sterm (8,1024)
__global__ void sterm_kernel(const float* __restrict__ shat, const float* __restrict__ attn_W,
                             const float* __restrict__ attn_b, float* __restrict__ sterm) {
    __shared__ float ss[8 * 1024];
    int tid = threadIdx.x;
    for (int i = tid; i < 8192; i += 256) ss[i] = shat[i];
    __syncthreads();
    int m = blockIdx.x * 4 + (tid >> 6);
    int lane = tid & 63;
    float acc[8] = {};
    for (int k = lane; k < 1024; k += 64) {
        float w = attn_W[(size_t)m * 2049 + 1024 + k];
        #pragma unroll
        for (int b = 0; b < 8; ++b) acc[b] += w * ss[b * 1024 + k];
    }
    #pragma unroll
    for (int b = 0; b < 8; ++b) acc[b] = wave_sum(acc[b]);
    if (lane == 0) {
        float ab = attn_b[m];
        #pragma unroll
        for (int b = 0; b < 8; ++b) sterm[b * 1024 + m] = acc[b] + ab;
    }
}

// ---------- K5: fused GEMM (r8/r11 verified). BM=BN=128, BK=64, 256 thr
// (2x2 waves). A staged f32 via global_load_lds (32B-chunk XOR swizzle,
// inverse on src), cvt f32->bf16 via v_perm at fragment read. B bf16
// gload_lds (16B-chunk swizzle). LDS 48KB -> 3 blocks/CU. 2-barrier loop.
__global__ __launch_bounds__(256, 3)
void attn_gemm_kernel(const float* __restrict__ h, const unsigned short* __restrict__ Whx,
                      const float* __restrict__ sterm, const float* __restrict__ coverage,
                      const float* __restrict__ wcf, const float* __restrict__ avf,
                      float* __restrict__ scores_part) {
    __shared__ uint4 As4[2048];   // 128 rows x 256 B (64 f32) = 32KB
    __shared__ uint4 Bs4[1024];   // 128 rows x 128 B (64 bf16) = 16KB
    char* As = (char*)As4;
    char* Bs = (char*)Bs4;
    int tid = threadIdx.x;
    // XCD swizzle: id = 64g + 8c + x -> rt = x + 8g (same XCD for all 8 ct), ct = c
    int id = blockIdx.x;
    int ct = (id >> 3) & 7;
    int rt = (id & 7) + ((id >> 6) << 3);
    int r0 = rt * 128, m0 = ct * 128;
    int lane = tid & 63, wid = tid >> 6;
    int wr = wid >> 1, wc = wid & 1;      // 2x2 waves, wave tile 64x64
    f32x4 acc[4][4] = {};

    // B staging: lane deposits 16B at row (i*32 + wid*8 + lane>>3), chunk lane&7.
    int lrowB = lane >> 3;
    int lsrcB = (lane & 7) ^ lrowB;
    // A staging (f32): row (i*16 + wid*4 + lane>>4), 16B-chunk c16 = lane&15.
    int rA7  = (wid * 4 + (lane >> 4)) & 7;
    int srcA = ((((lane & 15) >> 1) ^ rA7) << 3) + ((lane & 1) << 2);

    for (int t = 0; t < 16; ++t) {
        int k0 = t * 64;
        const float* hA = h + (size_t)r0 * 1024 + k0;
        const unsigned short* wB = Whx + (size_t)m0 * 1024 + k0;
        #pragma unroll
        for (int i = 0; i < 8; ++i) {   // A: 8 x 4KB (16 rows each)
            int row = i * 16 + wid * 4 + (lane >> 4);
            gl16(hA + (size_t)row * 1024 + srcA, As + i * 4096 + wid * 1024);
        }
        #pragma unroll
        for (int i = 0; i < 4; ++i) {   // B: 4 x 4KB (32 rows each)
            int row = i * 32 + wid * 8 + lrowB;
            gl16(wB + (size_t)row * 1024 + lsrcB * 8, Bs + i * 4096 + wid * 1024);
        }
        __syncthreads();   // compiler inserts vmcnt(0): deposits complete

        #pragma unroll
        for (int kh = 0; kh < 2; ++kh) {
            int cb = kh * 4 + (lane >> 4);
            bf16x8 af[4], bfr[4];
            #pragma unroll
            for (int mi = 0; mi < 4; ++mi) {
                int row = wr * 64 + mi * 16 + (lane & 15);
                int pc = (cb ^ (row & 7)) << 5;   // phys 32B chunk
                uint4 lo = *reinterpret_cast<const uint4*>(As + row * 256 + pc);
                uint4 hi = *reinterpret_cast<const uint4*>(As + row * 256 + pc + 16);
                uint4 pk;
                pk.x = __builtin_amdgcn_perm(lo.y, lo.x, 0x07060302u);
                pk.y = __builtin_amdgcn_perm(lo.w, lo.z, 0x07060302u);
                pk.z = __builtin_amdgcn_perm(hi.y, hi.x, 0x07060302u);
                pk.w = __builtin_amdgcn_perm(hi.w, hi.z, 0x07060302u);
                af[mi] = *reinterpret_cast<bf16x8*>(&pk);
            }
            #pragma unroll
            for (int ni = 0; ni < 4; ++ni) {
                int row = wc * 64 + ni * 16 + (lane & 15);
                bfr[ni] = *reinterpret_cast<const bf16x8*>(Bs + row * 128 + ((cb ^ (row & 7)) << 4));
            }
            #pragma unroll
            for (int mi = 0; mi < 4; ++mi)
                #pragma unroll
                for (int ni = 0; ni < 4; ++ni)
                    acc[mi][ni] = __builtin_amdgcn_mfma_f32_16x16x32_bf16(af[mi], bfr[ni], acc[mi][ni], 0, 0, 0);
        }
        __syncthreads();   // readers done before next overwrite
    }

    // epilogue: bias + tanh + dot attn_v, reduce over this tile's 128 columns.
    float* red = (float*)As4;   // overlays As after barrier below
    int b = r0 >> 13;
    float covv[4][4];
    #pragma unroll
    for (int mi = 0; mi < 4; ++mi)
        #pragma unroll
        for (int j = 0; j < 4; ++j)
            covv[mi][j] = coverage[r0 + wr * 64 + mi * 16 + ((lane >> 4) << 2) + j];
    float rs[4][4] = {};
    #pragma unroll
    for (int ni = 0; ni < 4; ++ni) {
        int m = m0 + wc * 64 + ni * 16 + (lane & 15);
        float stm = sterm[b * 1024 + m];
        float wcm = wcf[m], avm = avf[m];
        #pragma unroll
        for (int mi = 0; mi < 4; ++mi)
            #pragma unroll
            for (int j = 0; j < 4; ++j) {
                float val = acc[mi][ni][j] + stm + covv[mi][j] * wcm;
                rs[mi][j] += tanhf(val) * avm;
            }
    }
    #pragma unroll
    for (int mi = 0; mi < 4; ++mi)
        #pragma unroll
        for (int j = 0; j < 4; ++j) {
            float v = rs[mi][j];
            v += __shfl_xor(v, 1); v += __shfl_xor(v, 2);
            v += __shfl_xor(v, 4); v += __shfl_xor(v, 8);
            rs[mi][j] = v;
        }
    __syncthreads();   // all waves past k-loop reads before red overlays As
    if ((lane & 15) == 0) {
        int g4 = lane >> 4;
        #pragma unroll
        for (int mi = 0; mi < 4; ++mi)
            #pragma unroll
            for (int j = 0; j < 4; ++j)
                red[(wr * 64 + mi * 16 + g4 * 4 + j) * 2 + wc] = rs[mi][j];
    }
    __syncthreads();
    if (tid < 128)
        scores_part[(size_t)ct * MTOT + r0 + tid] = red[tid * 2] + red[tid * 2 + 1];
}

// ---------- K6: softmax over L per batch; attn, coverage_next (f32). 1024 thr.
__global__ void softmax_cov_kernel(const float* __restrict__ scores_part,
                                   const float* __restrict__ coverage,
                                   float* __restrict__ attn_out,
                                   float* __restrict__ cov_out,
                                   float* __restrict__ attnf) {
    __shared__ float s[8192];
    __shared__ float wred[16];
    int b = blockIdx.x, tid = threadIdx.x;
    int lane = tid & 63, wid = tid >> 6;
    float lmax = -1e30f;
    for (int l = tid; l < 8192; l += 1024) {
        float v = 0.f;
        #pragma unroll
        for (int p = 0; p < 8; ++p) v += scores_part[(size_t)p * MTOT + b * 8192 + l];
        s[l] = v;
        lmax = fmaxf(lmax, v);
    }
    #pragma unroll
    for (int o = 32; o; o >>= 1) lmax = fmaxf(lmax, __shfl_xor(lmax, o));
    if (lane == 0) wred[wid] = lmax;
    __syncthreads();
    float bmax = wred[0];
    #pragma unroll
    for (int i = 1; i < 16; ++i) bmax = fmaxf(bmax, wred[i]);
    float lsum = 0.f;
    for (int l = tid; l < 8192; l += 1024) {
        float e = expf(s[l] - bmax);
        s[l] = e;
        lsum += e;
    }
    lsum = wave_sum(lsum);
    __syncthreads();
    if (lane == 0) wred[wid] = lsum;
    __syncthreads();
    float tsum = 0.f;
    #pragma unroll
    for (int i = 0; i < 16; ++i) tsum += wred[i];
    float inv = 1.0f / tsum;
    for (int l = tid; l < 8192; l += 1024) {
        float a = s[l] * inv;
        attnf[b * 8192 + l] = a;
        attn_out[b * 8192 + l] = a;
        cov_out[b * 8192 + l] = coverage[b * 8192 + l] + a;
    }
}

// ---------- K7: c_t partial sums over L chunks (reads f32 h, memory-bound)
__global__ void ct_partial_kernel(const float* __restrict__ h,
                                  const float* __restrict__ attnf, float* __restrict__ ct_part) {
    int blk = blockIdx.x;           // 512 = 8 b x 64 chunks
    int b = blk >> 6, ch = blk & 63;
    int tid = threadIdx.x;
    float a0 = 0, a1 = 0, a2 = 0, a3 = 0;
    int rbase = b * 8192 + ch * 128;
    for (int l = 0; l < 128; ++l) {
        float a = attnf[rbase + l];
        float4 hv = *reinterpret_cast<const float4*>(h + (size_t)(rbase + l) * 1024 + tid * 4);
        a0 += a * hv.x; a1 += a * hv.y; a2 += a * hv.z; a3 += a * hv.w;
    }
    float4 o; o.x = a0; o.y = a1; o.z = a2; o.w = a3;
    *reinterpret_cast<float4*>(ct_part + (size_t)blk * 1024 + tid * 4) = o;
}

__global__ void ct_reduce_kernel(const float* __restrict__ ct_part, float* __restrict__ ctf,
                                 float* __restrict__ ct_out) {
    int idx = blockIdx.x * 256 + threadIdx.x;   // 8192
    int b = idx >> 10, n = idx & 1023;
    const float* p = ct_part + (size_t)b * 64 * 1024 + n;
    float s = 0.f;
    #pragma unroll 8
    for (int c = 0; c < 64; ++c) s += p[c * 1024];
    ctf[idx] = s;
    ct_out[idx] = s;
}

// ---------- K8a: u = concat(h_new, c_t) @ V_W.T + V_b  -> ws_u (8,512)
__global__ void u_kernel(const float* __restrict__ shat, const float* __restrict__ ctf,
                         const float* __restrict__ V_W, const float* __restrict__ V_b,
                         float* __restrict__ u) {
    __shared__ float cat[8 * 1536];
    int tid = threadIdx.x;
    for (int idx = tid; idx < 8 * 1536; idx += 256) {
        int b = idx / 1536, k = idx - b * 1536;
        cat[idx] = (k < 512) ? shat[b * 1024 + k] : ctf[b * 1024 + (k - 512)];
    }
    __syncthreads();
    int i = blockIdx.x * 4 + (tid >> 6);
    int lane = tid & 63;
    float acc[8] = {};
    for (int k = lane; k < 1536; k += 64) {
        float w = V_W[(size_t)i * 1536 + k];
        #pragma unroll
        for (int b = 0; b < 8; ++b) acc[b] += w * cat[b * 1536 + k];
    }
    #pragma unroll
    for (int b = 0; b < 8; ++b) acc[b] = wave_sum(acc[b]);
    if (lane == 0) {
        float vb = V_b[i];
        #pragma unroll
        for (int b = 0; b < 8; ++b) u[b * 512 + i] = acc[b] + vb;
    }
}

// ---------- K8p: p_gen = sigmoid(concat(c_t, s_hat, x)·pgen_W + pgen_b)
__global__ void pgen_kernel(const float* __restrict__ ctf, const float* __restrict__ shat,
                            const float* __restrict__ x, const float* __restrict__ pgen_W,
                            const float* __restrict__ pgen_b,
                            float* __restrict__ pgenf, float* __restrict__ pgen_out) {
    int tid = threadIdx.x;   // 512 threads, wave b
    int b = tid >> 6, lane = tid & 63;
    float acc = 0.f;
    for (int k = lane; k < 2304; k += 64) {
        float v;
        if (k < 1024)      v = ctf[b * 1024 + k];
        else if (k < 2048) v = shat[b * 1024 + (k - 1024)];
        else               v = x[b * 256 + (k - 2048)];
        acc += pgen_W[k] * v;
    }
    acc = wave_sum(acc);
    if (lane == 0) {
        float p = sigf(acc + pgen_b[0]);
        pgenf[b] = p;
        pgen_out[b] = p;
    }
}

// ---------- K8b: logits = u @ Vp_W.T + Vp_b  -> ws_logits (8,8192)
__global__ void logits_kernel(const float* __restrict__ u, const float* __restrict__ Vp_W,
                              const float* __restrict__ Vp_b, float* __restrict__ logits) {
    __shared__ float us[8 * 512];
    int tid = threadIdx.x;
    for (int i = tid; i < 4096; i += 256) us[i] = u[i];
    __syncthreads();
    int v = blockIdx.x * 4 + (tid >> 6);
    int lane = tid & 63;
    float acc[8] = {};
    for (int k = lane; k < 512; k += 64) {
        float w = Vp_W[(size_t)v * 512 + k];
        #pragma unroll
        for (int b = 0; b < 8; ++b) acc[b] += w * us[b * 512 + k];
    }
    #pragma unroll
    for (int b = 0; b < 8; ++b) acc[b] = wave_sum(acc[b]);
    if (lane == 0) {
        float vb = Vp_b[v];
        #pragma unroll
        for (int b = 0; b < 8; ++b) logits[b * 8192 + v] = acc[b] + vb;
    }
}

// ---------- K8c: P_vocab = softmax(logits); P_w = pg*P_vocab + (1-pg)*attn. 1024 thr.
__global__ void final_kernel(const float* __restrict__ logits, const float* __restrict__ pgenf,
                             const float* __restrict__ attnf, float* __restrict__ pw_out) {
    __shared__ float s[8192];
    __shared__ float wred[16];
    int b = blockIdx.x, tid = threadIdx.x;
    int lane = tid & 63, wid = tid >> 6;
    float lmax = -1e30f;
    for (int l = tid; l < 8192; l += 1024) {
        float v = logits[b * 8192 + l];
        s[l] = v;
        lmax = fmaxf(lmax, v);
    }
    #pragma unroll
    for (int o = 32; o; o >>= 1) lmax = fmaxf(lmax, __shfl_xor(lmax, o));
    if (lane == 0) wred[wid] = lmax;
    __syncthreads();
    float bmax = wred[0];
    #pragma unroll
    for (int i = 1; i < 16; ++i) bmax = fmaxf(bmax, wred[i]);
    float lsum = 0.f;
    for (int l = tid; l < 8192; l += 1024) {
        float e = expf(s[l] - bmax);
        s[l] = e;
        lsum += e;
    }
    lsum = wave_sum(lsum);
    __syncthreads();
    if (lane == 0) wred[wid] = lsum;
    __syncthreads();
    float tsum = 0.f;
    #pragma unroll
    for (int i = 0; i < 16; ++i) tsum += wred[i];
    float inv = 1.0f / tsum;
    float pg = pgenf[b];
    for (int l = tid; l < 8192; l += 1024) {
        float pv = s[l] * inv;
        pw_out[b * 8192 + l] = pg * pv + (1.0f - pg) * attnf[b * 8192 + l];
    }
}

extern "C" void kernel_launch(void* const* d_in, const int* in_sizes, int n_in,
                              void* d_out, int out_size, void* d_ws, size_t ws_size,
                              hipStream_t stream) {
    (void)in_sizes; (void)n_in; (void)out_size; (void)ws_size;
    const float* h        = (const float*)d_in[0];
    const float* s_h      = (const float*)d_in[1];
    const float* s_c      = (const float*)d_in[2];
    const int*   y_prev   = (const int*)d_in[3];
    const float* c_t_pre  = (const float*)d_in[4];
    const float* coverage = (const float*)d_in[5];
    const float* emb      = (const float*)d_in[6];
    const float* feed_W   = (const float*)d_in[7];
    const float* feed_b   = (const float*)d_in[8];
    const float* Wih      = (const float*)d_in[9];
    const float* Whh      = (const float*)d_in[10];
    const float* bih      = (const float*)d_in[11];
    const float* bhh      = (const float*)d_in[12];
    const float* attn_W   = (const float*)d_in[13];
    const float* attn_b   = (const float*)d_in[14];
    const float* attn_v   = (const float*)d_in[15];
    const float* pgen_W   = (const float*)d_in[16];
    const float* pgen_b   = (const float*)d_in[17];
    const float* V_W      = (const float*)d_in[18];
    const float* V_b      = (const float*)d_in[19];
    const float* Vp_W     = (const float*)d_in[20];
    const float* Vp_b     = (const float*)d_in[21];

    float* out    = (float*)d_out;
    float* o_pw   = out;
    float* o_attn = out + 65536;
    float* o_ct   = out + 131072;
    float* o_cov  = out + 139264;
    float* o_hnew = out + 204800;
    float* o_cnew = out + 208896;
    float* o_pgen = out + 212992;

    float* ws = (float*)d_ws;
    float* ws_x       = ws;
    float* ws_gates   = ws + 2048;
    float* ws_shat    = ws + 18432;
    float* ws_sterm   = ws + 26624;
    float* ws_u       = ws + 34816;
    float* ws_logits  = ws + 38912;
    float* ws_pgen    = ws + 104448;
    float* ws_wc      = ws + 105472;
    float* ws_av      = ws + 106496;
    float* ws_attnf   = ws + 107520;
    float* ws_scoresp = ws + 173056;   // 8 x 65536
    float* ws_ctpart  = ws + 697344;   // 512 x 1024
    float* ws_ctf     = ws + 1221632;  // 8192
    unsigned short* ws_whx = (unsigned short*)(ws + 1229824);  // 1024x1024 bf16 (2MB)

    pre_kernel<<<1088, 256, 0, stream>>>(attn_W, attn_v, ws_whx, ws_wc, ws_av,
                                         y_prev, emb, c_t_pre, feed_W, feed_b, ws_x);
    gates_kernel<<<512, 256, 0, stream>>>(ws_x, s_h, Wih, Whh, bih, bhh, ws_gates);
    lstm_kernel<<<16, 256, 0, stream>>>(ws_gates, s_c, o_hnew, o_cnew, ws_shat);
    sterm_kernel<<<256, 256, 0, stream>>>(ws_shat, attn_W, attn_b, ws_sterm);
    attn_gemm_kernel<<<4096, 256, 0, stream>>>(h, ws_whx, ws_sterm, coverage,
                                               ws_wc, ws_av, ws_scoresp);
    softmax_cov_kernel<<<8, 1024, 0, stream>>>(ws_scoresp, coverage, o_attn, o_cov, ws_attnf);
    ct_partial_kernel<<<512, 256, 0, stream>>>(h, ws_attnf, ws_ctpart);
    ct_reduce_kernel<<<32, 256, 0, stream>>>(ws_ctpart, ws_ctf, o_ct);
    u_kernel<<<128, 256, 0, stream>>>(ws_shat, ws_ctf, V_W, V_b, ws_u);
    pgen_kernel<<<1, 512, 0, stream>>>(ws_ctf, ws_shat, ws_x, pgen_W, pgen_b, ws_pgen, o_pgen);
    logits_kernel<<<2048, 256, 0, stream>>>(ws_u, Vp_W, Vp_b, ws_logits);
    final_kernel<<<8, 1024, 0, stream>>>(ws_logits, ws_pgen, ws_attnf, o_pw);
}